// Round 6
// baseline (393.515 us; speedup 1.0000x reference)
//
#include <hip/hip_runtime.h>
#include <hip/hip_bf16.h>
#include <math.h>

#define B_ 8
#define S_ 512
#define E_ 768
#define H_ 12
#define HE_ (H_ * E_)
#define KSPLIT 16
#define KCHUNK (HE_ / KSPLIT)  // 576 = 9*64

typedef __attribute__((ext_vector_type(8))) short bf16x8;
typedef __attribute__((ext_vector_type(4))) float f32x4;

__device__ inline void gload_lds16(const void* g, void* l) {
  __builtin_amdgcn_global_load_lds(
      (const __attribute__((address_space(1))) unsigned int*)g,
      (__attribute__((address_space(3))) unsigned int*)l, 16, 0, 0);
}

__device__ inline float tof(float v) { return v; }
__device__ inline float tof(__hip_bfloat16 v) { return __bfloat162float(v); }

// ---------- f32 -> bf16 convert ----------
__global__ __launch_bounds__(256) void cvt_kernel(const float* __restrict__ in,
                                                  __hip_bfloat16* __restrict__ out, int n) {
  int i = blockIdx.x * 256 + threadIdx.x;
  if (i < n) out[i] = __float2bfloat16(in[i]);
}

// ---------- transpose [R][C] -> bf16 [C][R], batched over z ----------
template <typename T>
__global__ __launch_bounds__(256) void transpose_kernel(const T* __restrict__ in, long inz,
                                                        __hip_bfloat16* __restrict__ out,
                                                        long outz, int R, int C) {
  __shared__ float t[32][33];
  in += (long)blockIdx.z * inz;
  out += (long)blockIdx.z * outz;
  int bc = blockIdx.x * 32, br = blockIdx.y * 32;
  int tx = threadIdx.x, ty = threadIdx.y;  // block (32,8)
#pragma unroll
  for (int i = ty; i < 32; i += 8) t[i][tx] = tof(in[(long)(br + i) * C + (bc + tx)]);
  __syncthreads();
#pragma unroll
  for (int i = ty; i < 32; i += 8)
    out[(long)(bc + i) * R + (br + tx)] = __float2bfloat16(t[tx][i]);
}

// ---------- 256x256 8-phase MFMA GEMM: C[M,N] = A[M,K] * (BT[N,K])^T ----------
// 512 threads = 8 waves (2M x 4N), per-wave 128x64 output, acc[8][4] f32x4.
// LDS: 2-deep double buffer, 128 KiB. Counted vmcnt(8) keeps next prefetch in
// flight across the tile-handoff barrier (T3+T4); raw s_barrier (NOT
// __syncthreads - that drains vmcnt). T5 setprio around MFMA clusters.
// Chunk-XOR LDS swizzle (verified r5): linear dest + inverse-swz source + swz read.
// Requires M%256==0, N%256==0, K%64==0, K>=128, grid%8==0.
template <bool OUT_BF16, bool ADD_BIAS>
__global__ __launch_bounds__(512) void gemm256(
    const __hip_bfloat16* __restrict__ A, long As1, long As2, int lda,
    const __hip_bfloat16* __restrict__ BT, long Bs1, long Bs2, int ldb,
    void* __restrict__ Cv, long Cs1, long Cs2, int ldc,
    const float* __restrict__ bias, long biasS2, int zmod, int K, float scale,
    int nx, int ny) {
  constexpr int BM = 256, BN = 256, BK = 64;
  constexpr int TSZ = BM * BK;  // 16384 elems per operand tile
  __shared__ __align__(16) __hip_bfloat16 sA[2][TSZ];
  __shared__ __align__(16) __hip_bfloat16 sB[2][TSZ];
  // T1: XCD-chunked bijective remap.
  const int nwg = gridDim.x, cpx = nwg >> 3, id = blockIdx.x;
  const int w = (id & 7) * cpx + (id >> 3);
  const int bz = w / (nx * ny);
  const int rem = w - bz * nx * ny;
  const int by = rem / nx, bx = rem - by * nx;

  const int tid = threadIdx.x, wave = tid >> 6, lane = tid & 63;
  const int r16 = lane & 15, g = lane >> 4;
  const int zb = bz / zmod, zh = bz % zmod;
  const int bm = by * BM, bn = bx * BN;
  A += (long)zb * As1 + (long)zh * As2 + (long)bm * lda;
  BT += (long)zb * Bs1 + (long)zh * Bs2 + (long)bn * ldb;
  const int wm = (wave >> 2) * 128, wn = (wave & 3) * 64;
  const int swz = (r16 & 7) << 3;
  f32x4 acc[8][4] = {};
  const int NT = K / BK;  // >= 8 for all our launches

  auto stage = [&](int t) {  // 8 gload_lds per thread per K-tile
    const __hip_bfloat16* gA = A + t * BK;
    const __hip_bfloat16* gB = BT + t * BK;
    __hip_bfloat16* dA = sA[t & 1];
    __hip_bfloat16* dB = sB[t & 1];
#pragma unroll
    for (int p = 0; p < 4; ++p) {
      int ee = p * 4096 + tid * 8;
      int row = ee >> 6;
      int col = (ee & 63) ^ ((row & 7) << 3);  // source-side inverse swizzle
      gload_lds16(gA + (long)row * lda + col, (char*)dA + ee * 2);
      gload_lds16(gB + (long)row * ldb + col, (char*)dB + ee * 2);
    }
  };

  // prologue: tiles 0 and 1 in flight; wait tile 0 only (8 of 16 retire).
  stage(0);
  stage(1);
  asm volatile("s_waitcnt vmcnt(8)" ::: "memory");
  __builtin_amdgcn_sched_barrier(0);
  __builtin_amdgcn_s_barrier();

  bf16x8 af[4][2], bh0[2][2], bh1[2][2];
  for (int t = 0; t < NT; ++t) {
    const __hip_bfloat16* sAc = sA[t & 1];
    const __hip_bfloat16* sBc = sB[t & 1];
    // ---- ph0: read A[mh0] + B[nh0]; MFMA quadrant (mh0, nh0)
#pragma unroll
    for (int mf = 0; mf < 4; ++mf)
#pragma unroll
      for (int ks = 0; ks < 2; ++ks)
        af[mf][ks] = *(const bf16x8*)(const void*)(sAc + (wm + mf * 16 + r16) * 64 +
                                                   ((ks * 32 + g * 8) ^ swz));
#pragma unroll
    for (int nf = 0; nf < 2; ++nf)
#pragma unroll
      for (int ks = 0; ks < 2; ++ks)
        bh0[nf][ks] = *(const bf16x8*)(const void*)(sBc + (wn + nf * 16 + r16) * 64 +
                                                    ((ks * 32 + g * 8) ^ swz));
    __builtin_amdgcn_s_setprio(1);
#pragma unroll
    for (int mf = 0; mf < 4; ++mf)
#pragma unroll
      for (int nf = 0; nf < 2; ++nf)
#pragma unroll
        for (int ks = 0; ks < 2; ++ks)
          acc[mf][nf] =
              __builtin_amdgcn_mfma_f32_16x16x32_bf16(af[mf][ks], bh0[nf][ks], acc[mf][nf], 0, 0, 0);
    __builtin_amdgcn_s_setprio(0);
    // ---- ph1: read A[mh1]; MFMA (mh1, nh0) reusing bh0
#pragma unroll
    for (int mf = 0; mf < 4; ++mf)
#pragma unroll
      for (int ks = 0; ks < 2; ++ks)
        af[mf][ks] = *(const bf16x8*)(const void*)(sAc + (wm + 64 + mf * 16 + r16) * 64 +
                                                   ((ks * 32 + g * 8) ^ swz));
    __builtin_amdgcn_s_setprio(1);
#pragma unroll
    for (int mf = 0; mf < 4; ++mf)
#pragma unroll
      for (int nf = 0; nf < 2; ++nf)
#pragma unroll
        for (int ks = 0; ks < 2; ++ks)
          acc[4 + mf][nf] =
              __builtin_amdgcn_mfma_f32_16x16x32_bf16(af[mf][ks], bh0[nf][ks], acc[4 + mf][nf], 0, 0, 0);
    __builtin_amdgcn_s_setprio(0);
    // ---- ph2: read B[nh1]; MFMA (mh1, nh1) reusing af (mh1)
#pragma unroll
    for (int nf = 0; nf < 2; ++nf)
#pragma unroll
      for (int ks = 0; ks < 2; ++ks)
        bh1[nf][ks] = *(const bf16x8*)(const void*)(sBc + (wn + 32 + nf * 16 + r16) * 64 +
                                                    ((ks * 32 + g * 8) ^ swz));
    __builtin_amdgcn_s_setprio(1);
#pragma unroll
    for (int mf = 0; mf < 4; ++mf)
#pragma unroll
      for (int nf = 0; nf < 2; ++nf)
#pragma unroll
        for (int ks = 0; ks < 2; ++ks)
          acc[4 + mf][2 + nf] =
              __builtin_amdgcn_mfma_f32_16x16x32_bf16(af[mf][ks], bh1[nf][ks], acc[4 + mf][2 + nf], 0, 0, 0);
    __builtin_amdgcn_s_setprio(0);
    // ---- ph3: re-read A[mh0]; all tile-t reads retired -> barrier -> overwrite-stage
#pragma unroll
    for (int mf = 0; mf < 4; ++mf)
#pragma unroll
      for (int ks = 0; ks < 2; ++ks)
        af[mf][ks] = *(const bf16x8*)(const void*)(sAc + (wm + mf * 16 + r16) * 64 +
                                                   ((ks * 32 + g * 8) ^ swz));
    asm volatile("s_waitcnt lgkmcnt(0)" ::: "memory");  // my reads of buf[cur] landed
    __builtin_amdgcn_sched_barrier(0);
    __builtin_amdgcn_s_barrier();                        // everyone's reads landed
    if (t + 2 < NT) stage(t + 2);                        // overwrite buf[cur] for tile t+2
    __builtin_amdgcn_s_setprio(1);
#pragma unroll
    for (int mf = 0; mf < 4; ++mf)
#pragma unroll
      for (int nf = 0; nf < 2; ++nf)
#pragma unroll
        for (int ks = 0; ks < 2; ++ks)
          acc[mf][2 + nf] =
              __builtin_amdgcn_mfma_f32_16x16x32_bf16(af[mf][ks], bh1[nf][ks], acc[mf][2 + nf], 0, 0, 0);
    __builtin_amdgcn_s_setprio(0);
    // ---- tile handoff: wait tile t+1 (counted - t+2's 8 loads stay in flight)
    if (t + 1 < NT) {
      if (t + 2 < NT)
        asm volatile("s_waitcnt vmcnt(8)" ::: "memory");
      else
        asm volatile("s_waitcnt vmcnt(0)" ::: "memory");
      __builtin_amdgcn_sched_barrier(0);
      __builtin_amdgcn_s_barrier();
    }
  }

  float* Cf = (float*)Cv;
  __hip_bfloat16* Cb = (__hip_bfloat16*)Cv;
  const long cbase = (long)zb * Cs1 + (long)zh * Cs2;
#pragma unroll
  for (int i = 0; i < 8; ++i) {
    int row0 = bm + wm + i * 16 + g * 4;
#pragma unroll
    for (int j = 0; j < 4; ++j) {
      int col = bn + wn + j * 16 + r16;
      float bv = ADD_BIAS ? bias[(long)zh * biasS2 + col] : 0.0f;
#pragma unroll
      for (int r = 0; r < 4; ++r) {
        float v = acc[i][j][r] * scale + bv;
        long off = cbase + (long)(row0 + r) * ldc + col;
        if (OUT_BF16)
          Cb[off] = __float2bfloat16(v);
        else
          Cf[off] = v;
      }
    }
  }
}

// ---------- masked softmax over rows of 512, bf16 in -> bf16 out, IN-PLACE ----------
__global__ __launch_bounds__(256) void softmax_kernel(__hip_bfloat16* __restrict__ scores,
                                                      const int* __restrict__ mask) {
  const int q = blockIdx.x, h = blockIdx.y, b = blockIdx.z;
  const int tid = threadIdx.x;
  const long base = (((long)b * H_ + h) * S_ + q) * S_;
  const int* mrow = mask + (long)b * S_;
  float v0 = __bfloat162float(scores[base + tid]);
  float v1 = __bfloat162float(scores[base + 256 + tid]);
  if (mrow[tid] == 1) v0 = -INFINITY;
  if (mrow[256 + tid] == 1) v1 = -INFINITY;
  float m = fmaxf(v0, v1);
#pragma unroll
  for (int o = 32; o; o >>= 1) m = fmaxf(m, __shfl_xor(m, o));
  __shared__ float red[8];
  const int wave = tid >> 6, lane = tid & 63;
  if (lane == 0) red[wave] = m;
  __syncthreads();
  m = fmaxf(fmaxf(red[0], red[1]), fmaxf(red[2], red[3]));
  float e0 = expf(v0 - m), e1 = expf(v1 - m);
  float s = e0 + e1;
#pragma unroll
  for (int o = 32; o; o >>= 1) s += __shfl_xor(s, o);
  if (lane == 0) red[4 + wave] = s;
  __syncthreads();
  s = red[4] + red[5] + red[6] + red[7];
  float inv = 1.0f / s;
  scores[base + tid] = __float2bfloat16(e0 * inv);
  scores[base + 256 + tid] = __float2bfloat16(e1 * inv);
}

// ---------- reduce KSPLIT bf16 partials + bias + LayerNorm over E=768 ----------
__global__ __launch_bounds__(256) void ln_kernel(const __hip_bfloat16* __restrict__ yp,
                                                 const float* __restrict__ bo,
                                                 const float* __restrict__ gamma,
                                                 const float* __restrict__ beta,
                                                 float* __restrict__ out) {
  const long nY = (long)B_ * S_ * E_;
  const long base = (long)blockIdx.x * E_;
  const int tid = threadIdx.x;
  float a = bo[tid], b = bo[256 + tid], c = bo[512 + tid];
#pragma unroll
  for (int k = 0; k < KSPLIT; ++k) {
    const __hip_bfloat16* y = yp + k * nY + base;
    a += __bfloat162float(y[tid]);
    b += __bfloat162float(y[256 + tid]);
    c += __bfloat162float(y[512 + tid]);
  }
  float s = a + b + c;
  float ss = a * a + b * b + c * c;
#pragma unroll
  for (int o = 32; o; o >>= 1) {
    s += __shfl_xor(s, o);
    ss += __shfl_xor(ss, o);
  }
  __shared__ float r1[4], r2[4];
  const int wave = tid >> 6, lane = tid & 63;
  if (lane == 0) { r1[wave] = s; r2[wave] = ss; }
  __syncthreads();
  s = r1[0] + r1[1] + r1[2] + r1[3];
  ss = r2[0] + r2[1] + r2[2] + r2[3];
  const float mu = s * (1.0f / E_);
  const float var = ss * (1.0f / E_) - mu * mu;
  const float rstd = rsqrtf(var + 1e-5f);
  out[base + tid] = (a - mu) * rstd * gamma[tid] + beta[tid];
  out[base + 256 + tid] = (b - mu) * rstd * gamma[256 + tid] + beta[256 + tid];
  out[base + 512 + tid] = (c - mu) * rstd * gamma[512 + tid] + beta[512 + tid];
}

extern "C" void kernel_launch(void* const* d_in, const int* in_sizes, int n_in,
                              void* d_out, int out_size, void* d_ws, size_t ws_size,
                              hipStream_t stream) {
  const float* x = (const float*)d_in[0];
  const int* mask = (const int*)d_in[1];
  const float* Wh = (const float*)d_in[2];
  const float* bh = (const float*)d_in[3];
  const float* Wo = (const float*)d_in[4];
  const float* bo = (const float*)d_in[5];
  const float* gamma = (const float*)d_in[6];
  const float* beta = (const float*)d_in[7];
  float* out = (float*)d_out;

  // ---- workspace: phase-aliased regions, total ~215.5 MB ----
  const size_t nX = (size_t)B_ * S_ * E_;        // 3,145,728
  const size_t nP = (size_t)B_ * H_ * S_ * E_;   // 37,748,736
  const size_t nSc = (size_t)B_ * H_ * S_ * S_;  // 25,165,824
  char* base = (char*)d_ws;
  // R_A: p, later cat (p dead after pT transpose + GEMM2)
  __hip_bfloat16* p = (__hip_bfloat16*)base;
  __hip_bfloat16* cat = p;
  char* RB = base + nP * 2;  // 75,497,472 B
  // R_B(+into R_C): pT, later 16 bf16 y-partials (16 x 6.29MB = 100.7MB; pT and
  // scores both dead at GEMM4 time; WoT at RB+125.8MB is untouched)
  __hip_bfloat16* pT = (__hip_bfloat16*)RB;
  __hip_bfloat16* ypart = (__hip_bfloat16*)RB;
  char* RC = RB + nP * 2;
  // R_C: xb + WhT early (dead after GEMM1), then scores/attn bf16 (in-place softmax)
  __hip_bfloat16* xb = (__hip_bfloat16*)RC;
  __hip_bfloat16* WhT = (__hip_bfloat16*)(RC + nX * 2);
  __hip_bfloat16* scores = (__hip_bfloat16*)RC;
  char* RD = RC + nSc * 2;
  // R_D: WoT (live until GEMM4)
  __hip_bfloat16* WoT = (__hip_bfloat16*)RD;

  dim3 t256(256), t512(512);
  dim3 tT(32, 8);
  const float inv_sqrtE = 1.0f / sqrtf((float)E_);

  // 1. x -> bf16
  cvt_kernel<<<dim3(nX / 256), t256, 0, stream>>>(x, xb, (int)nX);
  // 2. WhT[h][o][e] = Wh[h][e][o]
  transpose_kernel<float><<<dim3(24, 24, 12), tT, 0, stream>>>(Wh, (long)E_ * E_, WhT,
                                                               (long)E_ * E_, E_, E_);
  // 3. WoT[o][k] = Wo[k][o]  (k over H*E)
  transpose_kernel<float><<<dim3(24, 288, 1), tT, 0, stream>>>(Wo, 0, WoT, 0, HE_, E_);
  // 4. p = x·Wh + bh   (bf16 out); M=512,N=768,K=768: grid 3x2x96 = 576
  gemm256<true, true><<<dim3(576), t512, 0, stream>>>(
      xb, (long)S_ * E_, 0, E_, WhT, 0, (long)E_ * E_, E_, p, (long)H_ * S_ * E_,
      (long)S_ * E_, E_, bh, E_, H_, E_, 1.0f, 3, 2);
  // 5. pT[b,h,e,s] = p[b,h,s,e]
  transpose_kernel<__hip_bfloat16><<<dim3(24, 16, B_ * H_), tT, 0, stream>>>(
      p, (long)S_ * E_, pT, (long)S_ * E_, S_, E_);
  // 6. scores = (p·p^T)/sqrt(E)  (bf16); M=N=512,K=768: grid 2x2x96 = 384
  gemm256<true, false><<<dim3(384), t512, 0, stream>>>(
      p, (long)H_ * S_ * E_, (long)S_ * E_, E_, p, (long)H_ * S_ * E_, (long)S_ * E_, E_,
      scores, (long)H_ * S_ * S_, (long)S_ * S_, S_, nullptr, 0, H_, E_, inv_sqrtE, 2, 2);
  // 7. masked softmax in-place -> attn (bf16)
  softmax_kernel<<<dim3(S_, H_, B_), t256, 0, stream>>>(scores, mask);
  // 8. o = attn·p -> cat[b,s,h*E+e]  (bf16); M=512,N=768,K=512: grid 3x2x96 = 576
  gemm256<true, false><<<dim3(576), t512, 0, stream>>>(
      scores, (long)H_ * S_ * S_, (long)S_ * S_, S_, pT, (long)H_ * E_ * S_, (long)E_ * S_,
      S_, cat, (long)S_ * HE_, (long)E_, HE_, nullptr, 0, H_, S_, 1.0f, 3, 2);
  // 9. split-K GEMM4: 16 chunks of K=576; M=4096,N=768: grid 3x16x16 = 768 (3 CU-rounds)
  gemm256<true, false><<<dim3(768), t512, 0, stream>>>(
      cat, 0, KCHUNK, HE_, WoT, 0, KCHUNK, HE_, ypart, 0, (long)B_ * S_ * E_, E_,
      nullptr, 0, KSPLIT, KCHUNK, 1.0f, 3, 16);
  // 10. reduce 16 partials + bias + LayerNorm -> out
  ln_kernel<<<dim3(B_ * S_), t256, 0, stream>>>(ypart, bo, gamma, beta, out);
}

// Round 7
// 309.723 us; speedup vs baseline: 1.2705x; 1.2705x over previous
//
#include <hip/hip_runtime.h>
#include <hip/hip_bf16.h>
#include <math.h>

#define B_ 8
#define S_ 512
#define E_ 768
#define H_ 12
#define HE_ (H_ * E_)
#define KSPLIT 6
#define KCHUNK (HE_ / KSPLIT)  // 1536

typedef __attribute__((ext_vector_type(4))) short bf16x4;
typedef __attribute__((ext_vector_type(8))) short bf16x8;
typedef __attribute__((ext_vector_type(4))) float f32x4;
typedef __attribute__((ext_vector_type(4))) int i32x4;

__device__ inline void gload_lds16(const void* g, void* l) {
  __builtin_amdgcn_global_load_lds(
      (const __attribute__((address_space(1))) unsigned int*)g,
      (__attribute__((address_space(3))) unsigned int*)l, 16, 0, 0);
}

__device__ inline float bf2f(short u) {
  union { float f; unsigned int i; } c;
  c.i = ((unsigned int)(unsigned short)u) << 16;
  return c.f;
}
__device__ inline short f2bf(float f) {
  __hip_bfloat16 h = __float2bfloat16(f);
  return *reinterpret_cast<short*>(&h);
}

// ---------- f32 -> bf16 convert, float4/lane ----------
__global__ __launch_bounds__(256) void cvt_v(const float* __restrict__ in,
                                             short* __restrict__ out) {
  const long i = ((long)blockIdx.x * 256 + threadIdx.x) * 4;
  float4 v = *reinterpret_cast<const float4*>(in + i);
  bf16x4 o;
  o[0] = f2bf(v.x); o[1] = f2bf(v.y); o[2] = f2bf(v.z); o[3] = f2bf(v.w);
  *reinterpret_cast<bf16x4*>(out + i) = o;
}

// ---------- vectorized transpose: in [R][C] (T=float|bf16 as short) -> bf16 out [C][R] ----------
// 64x64 tile, 16B/lane global on both phases, f32 LDS stage [64][65] (<=2-way banks).
template <typename T, int VW>
__global__ __launch_bounds__(256) void transpose_v(const T* __restrict__ in, long inz,
                                                   short* __restrict__ out, long outz,
                                                   int R, int C) {
  __shared__ float t[64][65];
  in += (long)blockIdx.z * inz;
  out += (long)blockIdx.z * outz;
  const int bc = blockIdx.x * 64, br = blockIdx.y * 64;
  const int tid = threadIdx.x;
  constexpr int CPR = 64 / VW;             // chunks per row
  constexpr int NP1 = 64 * CPR / 256;      // passes in phase 1
#pragma unroll
  for (int ps = 0; ps < NP1; ++ps) {
    int q = tid + ps * 256;
    int r = q / CPR, c0 = (q % CPR) * VW;
    const T* src = in + (long)(br + r) * C + bc + c0;
    if constexpr (VW == 4) {
      float4 v = *reinterpret_cast<const float4*>(src);
      t[r][c0] = v.x; t[r][c0 + 1] = v.y; t[r][c0 + 2] = v.z; t[r][c0 + 3] = v.w;
    } else {
      bf16x8 v = *reinterpret_cast<const bf16x8*>(src);
#pragma unroll
      for (int j = 0; j < 8; ++j) t[r][c0 + j] = bf2f(v[j]);
    }
  }
  __syncthreads();
#pragma unroll
  for (int ps = 0; ps < 2; ++ps) {
    int q = tid + ps * 256;
    int e = q >> 3, s0 = (q & 7) * 8;
    bf16x8 o;
#pragma unroll
    for (int j = 0; j < 8; ++j) o[j] = f2bf(t[s0 + j][e]);
    *reinterpret_cast<bf16x8*>(out + (long)(bc + e) * R + br + s0) = o;
  }
}

// ---------- MFMA GEMM: C[M,N] = A[M,K] * (BT[N,K])^T, bf16 in, fp32 accum ----------
// (verified r5 kernel: T1 XCD swizzle + chunk-XOR LDS swizzle, conflicts == 0)
template <bool OUT_BF16, bool ADD_BIAS>
__global__ __launch_bounds__(256) void gemm_bt(
    const __hip_bfloat16* __restrict__ A, long As1, long As2, int lda,
    const __hip_bfloat16* __restrict__ BT, long Bs1, long Bs2, int ldb,
    void* __restrict__ Cv, long Cs1, long Cs2, int ldc,
    const float* __restrict__ bias, long biasS2, int zmod, int K, float scale,
    int nx, int ny) {
  constexpr int BM = 128, BN = 128, BK = 64;
  __shared__ __align__(16) __hip_bfloat16 sA[BM * BK];
  __shared__ __align__(16) __hip_bfloat16 sB[BN * BK];
  const int nwg = gridDim.x;
  const int cpx = nwg >> 3;
  const int id = blockIdx.x;
  const int w = (id & 7) * cpx + (id >> 3);
  const int bz = w / (nx * ny);
  const int rem = w - bz * nx * ny;
  const int by = rem / nx;
  const int bx = rem - by * nx;

  const int tid = threadIdx.x;
  const int wave = tid >> 6, lane = tid & 63;
  const int r16 = lane & 15, g = lane >> 4;
  const int zb = bz / zmod, zh = bz % zmod;
  A += (long)zb * As1 + (long)zh * As2;
  BT += (long)zb * Bs1 + (long)zh * Bs2;
  const int bm = by * BM, bn = bx * BN;
  const int wm = (wave >> 1) * 64, wn = (wave & 1) * 64;
  f32x4 acc[4][4] = {};
  const int e0 = tid * 8;

  for (int k0 = 0; k0 < K; k0 += BK) {
#pragma unroll
    for (int p = 0; p < 4; ++p) {
      int ee = p * 2048 + e0;
      int row = ee >> 6;
      int col = (ee & 63) ^ ((row & 7) << 3);  // source-side inverse swizzle
      gload_lds16(A + (long)(bm + row) * lda + (k0 + col), (char*)sA + ee * 2);
      gload_lds16(BT + (long)(bn + row) * ldb + (k0 + col), (char*)sB + ee * 2);
    }
    __syncthreads();
#pragma unroll
    for (int kk = 0; kk < BK; kk += 32) {
      bf16x8 af[4], bfr[4];
#pragma unroll
      for (int i = 0; i < 4; ++i) {
        int row = wm + i * 16 + r16;
        int c = (kk + g * 8) ^ ((row & 7) << 3);  // read-side swizzle
        af[i] = *(const bf16x8*)(const void*)(sA + row * BK + c);
      }
#pragma unroll
      for (int j = 0; j < 4; ++j) {
        int row = wn + j * 16 + r16;
        int c = (kk + g * 8) ^ ((row & 7) << 3);
        bfr[j] = *(const bf16x8*)(const void*)(sB + row * BK + c);
      }
#pragma unroll
      for (int i = 0; i < 4; ++i)
#pragma unroll
        for (int j = 0; j < 4; ++j)
          acc[i][j] = __builtin_amdgcn_mfma_f32_16x16x32_bf16(af[i], bfr[j], acc[i][j], 0, 0, 0);
    }
    __syncthreads();
  }

  float* Cf = (float*)Cv;
  __hip_bfloat16* Cb = (__hip_bfloat16*)Cv;
  const long cbase = (long)zb * Cs1 + (long)zh * Cs2;
#pragma unroll
  for (int i = 0; i < 4; ++i) {
    int row0 = bm + wm + i * 16 + g * 4;
#pragma unroll
    for (int j = 0; j < 4; ++j) {
      int col = bn + wn + j * 16 + r16;
      float bv = ADD_BIAS ? bias[(long)zh * biasS2 + col] : 0.0f;
#pragma unroll
      for (int r = 0; r < 4; ++r) {
        float v = acc[i][j][r] * scale + bv;
        long off = cbase + (long)(row0 + r) * ldc + col;
        if (OUT_BF16)
          Cb[off] = __float2bfloat16(v);
        else
          Cf[off] = v;
      }
    }
  }
}

// ---------- masked softmax, wave-per-row, bf16x8 loads, IN-PLACE ----------
__global__ __launch_bounds__(256) void softmax_v(__hip_bfloat16* __restrict__ scores,
                                                 const int* __restrict__ mask) {
  const int wave = threadIdx.x >> 6, lane = threadIdx.x & 63;
  const long row = (long)blockIdx.x * 4 + wave;
  const int b = (int)(row / ((long)H_ * S_));
  short* sp = (short*)scores + row * S_ + lane * 8;
  bf16x8 sv = *reinterpret_cast<const bf16x8*>(sp);
  const int* mrow = mask + (long)b * S_ + lane * 8;
  i32x4 m0 = *reinterpret_cast<const i32x4*>(mrow);
  i32x4 m1 = *reinterpret_cast<const i32x4*>(mrow + 4);
  float v[8];
#pragma unroll
  for (int j = 0; j < 8; ++j) v[j] = bf2f(sv[j]);
  if (m0[0] == 1) v[0] = -INFINITY;
  if (m0[1] == 1) v[1] = -INFINITY;
  if (m0[2] == 1) v[2] = -INFINITY;
  if (m0[3] == 1) v[3] = -INFINITY;
  if (m1[0] == 1) v[4] = -INFINITY;
  if (m1[1] == 1) v[5] = -INFINITY;
  if (m1[2] == 1) v[6] = -INFINITY;
  if (m1[3] == 1) v[7] = -INFINITY;
  float mx = v[0];
#pragma unroll
  for (int j = 1; j < 8; ++j) mx = fmaxf(mx, v[j]);
#pragma unroll
  for (int o = 32; o; o >>= 1) mx = fmaxf(mx, __shfl_xor(mx, o));
  float e[8], s = 0.0f;
#pragma unroll
  for (int j = 0; j < 8; ++j) {
    e[j] = expf(v[j] - mx);
    s += e[j];
  }
#pragma unroll
  for (int o = 32; o; o >>= 1) s += __shfl_xor(s, o);
  const float inv = 1.0f / s;
  bf16x8 o8;
#pragma unroll
  for (int j = 0; j < 8; ++j) o8[j] = f2bf(e[j] * inv);
  *reinterpret_cast<bf16x8*>(sp) = o8;
}

// ---------- reduce KSPLIT bf16 partials + bias + LayerNorm, vectorized ----------
__global__ __launch_bounds__(192) void ln_v(const __hip_bfloat16* __restrict__ yp,
                                            const float* __restrict__ bo,
                                            const float* __restrict__ gamma,
                                            const float* __restrict__ beta,
                                            float* __restrict__ out) {
  const long nY = (long)B_ * S_ * E_;
  const long base = (long)blockIdx.x * E_;
  const int t = threadIdx.x;  // 0..191, chunk of 4 elems
  const int c0 = t * 4;
  float a[4];
  {
    float4 bv = *reinterpret_cast<const float4*>(bo + c0);
    a[0] = bv.x; a[1] = bv.y; a[2] = bv.z; a[3] = bv.w;
  }
#pragma unroll
  for (int k = 0; k < KSPLIT; ++k) {
    bf16x4 v = *reinterpret_cast<const bf16x4*>((const short*)yp + k * nY + base + c0);
#pragma unroll
    for (int j = 0; j < 4; ++j) a[j] += bf2f(v[j]);
  }
  float s = a[0] + a[1] + a[2] + a[3];
  float ss = a[0] * a[0] + a[1] * a[1] + a[2] * a[2] + a[3] * a[3];
#pragma unroll
  for (int o = 32; o; o >>= 1) {
    s += __shfl_xor(s, o);
    ss += __shfl_xor(ss, o);
  }
  __shared__ float r1[3], r2[3];
  const int wave = t >> 6, lane = t & 63;
  if (lane == 0) { r1[wave] = s; r2[wave] = ss; }
  __syncthreads();
  s = r1[0] + r1[1] + r1[2];
  ss = r2[0] + r2[1] + r2[2];
  const float mu = s * (1.0f / E_);
  const float var = ss * (1.0f / E_) - mu * mu;
  const float rstd = rsqrtf(var + 1e-5f);
  float4 g = *reinterpret_cast<const float4*>(gamma + c0);
  float4 bt = *reinterpret_cast<const float4*>(beta + c0);
  float4 o4;
  o4.x = (a[0] - mu) * rstd * g.x + bt.x;
  o4.y = (a[1] - mu) * rstd * g.y + bt.y;
  o4.z = (a[2] - mu) * rstd * g.z + bt.z;
  o4.w = (a[3] - mu) * rstd * g.w + bt.w;
  *reinterpret_cast<float4*>(out + base + c0) = o4;
}

extern "C" void kernel_launch(void* const* d_in, const int* in_sizes, int n_in,
                              void* d_out, int out_size, void* d_ws, size_t ws_size,
                              hipStream_t stream) {
  const float* x = (const float*)d_in[0];
  const int* mask = (const int*)d_in[1];
  const float* Wh = (const float*)d_in[2];
  const float* bh = (const float*)d_in[3];
  const float* Wo = (const float*)d_in[4];
  const float* bo = (const float*)d_in[5];
  const float* gamma = (const float*)d_in[6];
  const float* beta = (const float*)d_in[7];
  float* out = (float*)d_out;

  // ---- workspace: phase-aliased regions (r5 layout, ~215.5 MB) ----
  const size_t nX = (size_t)B_ * S_ * E_;        // 3,145,728
  const size_t nP = (size_t)B_ * H_ * S_ * E_;   // 37,748,736
  const size_t nSc = (size_t)B_ * H_ * S_ * S_;  // 25,165,824
  char* base = (char*)d_ws;
  __hip_bfloat16* p = (__hip_bfloat16*)base;  // R_A: p, later cat
  __hip_bfloat16* cat = p;
  char* RB = base + nP * 2;
  __hip_bfloat16* pT = (__hip_bfloat16*)RB;       // R_B: pT, later ypart (6x6.3MB bf16)
  __hip_bfloat16* ypart = (__hip_bfloat16*)RB;
  char* RC = RB + nP * 2;
  __hip_bfloat16* xb = (__hip_bfloat16*)RC;       // R_C: xb+WhT, later scores/attn
  __hip_bfloat16* WhT = (__hip_bfloat16*)(RC + nX * 2);
  __hip_bfloat16* scores = (__hip_bfloat16*)RC;
  char* RD = RC + nSc * 2;
  __hip_bfloat16* WoT = (__hip_bfloat16*)RD;      // R_D: WoT

  dim3 t256(256);
  const float inv_sqrtE = 1.0f / sqrtf((float)E_);

  // 1. x -> bf16 (float4; 3072 blocks exact)
  cvt_v<<<dim3(nX / 1024), t256, 0, stream>>>(x, (short*)xb);
  // 2. WhT[h][o][e] = Wh[h][e][o]
  transpose_v<float, 4><<<dim3(12, 12, 12), t256, 0, stream>>>(
      Wh, (long)E_ * E_, (short*)WhT, (long)E_ * E_, E_, E_);
  // 3. WoT[o][k] = Wo[k][o]
  transpose_v<float, 4><<<dim3(12, 144, 1), t256, 0, stream>>>(
      Wo, 0, (short*)WoT, 0, HE_, E_);
  // 4. p = x·Wh + bh   (grid 6x4x96 = 2304)
  gemm_bt<true, true><<<dim3(6 * 4 * 96), t256, 0, stream>>>(
      xb, (long)S_ * E_, 0, E_, WhT, 0, (long)E_ * E_, E_, p, (long)H_ * S_ * E_,
      (long)S_ * E_, E_, bh, E_, H_, E_, 1.0f, 6, 4);
  // 5. pT[b,h,e,s] = p[b,h,s,e]  (vectorized)
  transpose_v<short, 8><<<dim3(12, 8, 96), t256, 0, stream>>>(
      (const short*)p, (long)S_ * E_, (short*)pT, (long)S_ * E_, S_, E_);
  // 6. scores = (p·p^T)/sqrt(E)  (grid 4x4x96 = 1536)
  gemm_bt<true, false><<<dim3(4 * 4 * 96), t256, 0, stream>>>(
      p, (long)H_ * S_ * E_, (long)S_ * E_, E_, p, (long)H_ * S_ * E_, (long)S_ * E_, E_,
      scores, (long)H_ * S_ * S_, (long)S_ * S_, S_, nullptr, 0, H_, E_, inv_sqrtE, 4, 4);
  // 7. masked softmax in-place (wave-per-row; 49152/4 blocks)
  softmax_v<<<dim3(12288), t256, 0, stream>>>(scores, mask);
  // 8. o = attn·p -> cat  (grid 6x4x96 = 2304)
  gemm_bt<true, false><<<dim3(6 * 4 * 96), t256, 0, stream>>>(
      scores, (long)H_ * S_ * S_, (long)S_ * S_, S_, pT, (long)H_ * E_ * S_, (long)E_ * S_,
      S_, cat, (long)S_ * HE_, (long)E_, HE_, nullptr, 0, H_, S_, 1.0f, 6, 4);
  // 9. split-K GEMM4 (grid 6x32x6 = 1152, bf16 partials)
  gemm_bt<true, false><<<dim3(6 * 32 * KSPLIT), t256, 0, stream>>>(
      cat, 0, KCHUNK, HE_, WoT, 0, KCHUNK, HE_, ypart, 0, (long)B_ * S_ * E_, E_,
      nullptr, 0, KSPLIT, KCHUNK, 1.0f, 6, 32);
  // 10. reduce partials + bias + LayerNorm (block 192, float4/bf16x4)
  ln_v<<<dim3(B_ * S_), dim3(192), 0, stream>>>(ypart, bo, gamma, beta, out);
}

// Round 8
// 306.875 us; speedup vs baseline: 1.2823x; 1.0093x over previous
//
#include <hip/hip_runtime.h>
#include <hip/hip_bf16.h>
#include <math.h>

#define B_ 8
#define S_ 512
#define E_ 768
#define H_ 12
#define HE_ (H_ * E_)
#define KSPLIT 6
#define KCHUNK (HE_ / KSPLIT)  // 1536

typedef __attribute__((ext_vector_type(4))) short bf16x4;
typedef __attribute__((ext_vector_type(8))) short bf16x8;
typedef __attribute__((ext_vector_type(4))) float f32x4;
typedef __attribute__((ext_vector_type(16))) float f32x16;
typedef __attribute__((ext_vector_type(4))) int i32x4;

__device__ inline void gload_lds16(const void* g, void* l) {
  __builtin_amdgcn_global_load_lds(
      (const __attribute__((address_space(1))) unsigned int*)g,
      (__attribute__((address_space(3))) unsigned int*)l, 16, 0, 0);
}

__device__ inline float bf2f(short u) {
  union { float f; unsigned int i; } c;
  c.i = ((unsigned int)(unsigned short)u) << 16;
  return c.f;
}
__device__ inline short f2bf(float f) {
  __hip_bfloat16 h = __float2bfloat16(f);
  return *reinterpret_cast<short*>(&h);
}

// ---------- f32 -> bf16 convert, float4/lane ----------
__global__ __launch_bounds__(256) void cvt_v(const float* __restrict__ in,
                                             short* __restrict__ out) {
  const long i = ((long)blockIdx.x * 256 + threadIdx.x) * 4;
  float4 v = *reinterpret_cast<const float4*>(in + i);
  bf16x4 o;
  o[0] = f2bf(v.x); o[1] = f2bf(v.y); o[2] = f2bf(v.z); o[3] = f2bf(v.w);
  *reinterpret_cast<bf16x4*>(out + i) = o;
}

// ---------- vectorized transpose: in [R][C] (T=float|bf16 as short) -> bf16 out [C][R] ----------
template <typename T, int VW>
__global__ __launch_bounds__(256) void transpose_v(const T* __restrict__ in, long inz,
                                                   short* __restrict__ out, long outz,
                                                   int R, int C) {
  __shared__ float t[64][65];
  in += (long)blockIdx.z * inz;
  out += (long)blockIdx.z * outz;
  const int bc = blockIdx.x * 64, br = blockIdx.y * 64;
  const int tid = threadIdx.x;
  constexpr int CPR = 64 / VW;
  constexpr int NP1 = 64 * CPR / 256;
#pragma unroll
  for (int ps = 0; ps < NP1; ++ps) {
    int q = tid + ps * 256;
    int r = q / CPR, c0 = (q % CPR) * VW;
    const T* src = in + (long)(br + r) * C + bc + c0;
    if constexpr (VW == 4) {
      float4 v = *reinterpret_cast<const float4*>(src);
      t[r][c0] = v.x; t[r][c0 + 1] = v.y; t[r][c0 + 2] = v.z; t[r][c0 + 3] = v.w;
    } else {
      bf16x8 v = *reinterpret_cast<const bf16x8*>(src);
#pragma unroll
      for (int j = 0; j < 8; ++j) t[r][c0 + j] = bf2f(v[j]);
    }
  }
  __syncthreads();
#pragma unroll
  for (int ps = 0; ps < 2; ++ps) {
    int q = tid + ps * 256;
    int e = q >> 3, s0 = (q & 7) * 8;
    bf16x8 o;
#pragma unroll
    for (int j = 0; j < 8; ++j) o[j] = f2bf(t[s0 + j][e]);
    *reinterpret_cast<bf16x8*>(out + (long)(bc + e) * R + br + s0) = o;
  }
}

// ---------- MFMA GEMM (32x32x16): C[M,N] = A[M,K] * (BT[N,K])^T ----------
// T1 XCD swizzle + chunk-XOR LDS swizzle (verified conflict-free r5/r7).
// Per wave: 64x64 output = 2x2 tiles of 32x32, acc f32x16 each.
// A-frag: row = lane&31, k-chunk = lane>>5 (8 contiguous k).  C/D: col=lane&31,
// row=(reg&3)+8*(reg>>2)+4*(lane>>5)  [HW-verified m74/m101].
template <bool OUT_BF16, bool ADD_BIAS>
__global__ __launch_bounds__(256) void gemm_bt(
    const __hip_bfloat16* __restrict__ A, long As1, long As2, int lda,
    const __hip_bfloat16* __restrict__ BT, long Bs1, long Bs2, int ldb,
    void* __restrict__ Cv, long Cs1, long Cs2, int ldc,
    const float* __restrict__ bias, long biasS2, int zmod, int K, float scale,
    int nx, int ny) {
  constexpr int BM = 128, BN = 128, BK = 64;
  __shared__ __align__(16) __hip_bfloat16 sA[BM * BK];
  __shared__ __align__(16) __hip_bfloat16 sB[BN * BK];
  const int nwg = gridDim.x;
  const int cpx = nwg >> 3;
  const int id = blockIdx.x;
  const int w = (id & 7) * cpx + (id >> 3);
  const int bz = w / (nx * ny);
  const int rem = w - bz * nx * ny;
  const int by = rem / nx;
  const int bx = rem - by * nx;

  const int tid = threadIdx.x;
  const int wave = tid >> 6, lane = tid & 63;
  const int r32 = lane & 31, g2 = lane >> 5;  // row/col within 32, k-group (2)
  const int zb = bz / zmod, zh = bz % zmod;
  A += (long)zb * As1 + (long)zh * As2;
  BT += (long)zb * Bs1 + (long)zh * Bs2;
  const int bm = by * BM, bn = bx * BN;
  const int wm = (wave >> 1) * 64, wn = (wave & 1) * 64;
  const int swz = (r32 & 7) << 3;  // per-lane XOR constant (row&7 == r32&7)
  f32x16 acc[2][2] = {};
  const int e0 = tid * 8;

  for (int k0 = 0; k0 < K; k0 += BK) {
#pragma unroll
    for (int p = 0; p < 4; ++p) {
      int ee = p * 2048 + e0;
      int row = ee >> 6;
      int col = (ee & 63) ^ ((row & 7) << 3);  // source-side inverse swizzle
      gload_lds16(A + (long)(bm + row) * lda + (k0 + col), (char*)sA + ee * 2);
      gload_lds16(BT + (long)(bn + row) * ldb + (k0 + col), (char*)sB + ee * 2);
    }
    __syncthreads();
#pragma unroll
    for (int ks = 0; ks < 4; ++ks) {  // K=16 slices
      bf16x8 aw[2], bw[2];
#pragma unroll
      for (int ti = 0; ti < 2; ++ti) {
        int row = wm + ti * 32 + r32;
        int c = (ks * 16 + g2 * 8) ^ swz;
        aw[ti] = *(const bf16x8*)(const void*)(sA + row * BK + c);
      }
#pragma unroll
      for (int tj = 0; tj < 2; ++tj) {
        int row = wn + tj * 32 + r32;
        int c = (ks * 16 + g2 * 8) ^ swz;
        bw[tj] = *(const bf16x8*)(const void*)(sB + row * BK + c);
      }
#pragma unroll
      for (int ti = 0; ti < 2; ++ti)
#pragma unroll
        for (int tj = 0; tj < 2; ++tj)
          acc[ti][tj] =
              __builtin_amdgcn_mfma_f32_32x32x16_bf16(aw[ti], bw[tj], acc[ti][tj], 0, 0, 0);
    }
    __syncthreads();
  }

  float* Cf = (float*)Cv;
  __hip_bfloat16* Cb = (__hip_bfloat16*)Cv;
  const long cbase = (long)zb * Cs1 + (long)zh * Cs2;
#pragma unroll
  for (int ti = 0; ti < 2; ++ti)
#pragma unroll
    for (int tj = 0; tj < 2; ++tj) {
      const int colv = bn + wn + tj * 32 + r32;
      const float bv = ADD_BIAS ? bias[(long)zh * biasS2 + colv] : 0.0f;
#pragma unroll
      for (int r = 0; r < 16; ++r) {
        int rowv = bm + wm + ti * 32 + (r & 3) + 8 * (r >> 2) + 4 * g2;
        float v = acc[ti][tj][r] * scale + bv;
        long off = cbase + (long)rowv * ldc + colv;
        if (OUT_BF16)
          Cb[off] = __float2bfloat16(v);
        else
          Cf[off] = v;
      }
    }
}

// ---------- masked softmax, wave-per-row, bf16x8 loads, IN-PLACE ----------
__global__ __launch_bounds__(256) void softmax_v(__hip_bfloat16* __restrict__ scores,
                                                 const int* __restrict__ mask) {
  const int wave = threadIdx.x >> 6, lane = threadIdx.x & 63;
  const long row = (long)blockIdx.x * 4 + wave;
  const int b = (int)(row / ((long)H_ * S_));
  short* sp = (short*)scores + row * S_ + lane * 8;
  bf16x8 sv = *reinterpret_cast<const bf16x8*>(sp);
  const int* mrow = mask + (long)b * S_ + lane * 8;
  i32x4 m0 = *reinterpret_cast<const i32x4*>(mrow);
  i32x4 m1 = *reinterpret_cast<const i32x4*>(mrow + 4);
  float v[8];
#pragma unroll
  for (int j = 0; j < 8; ++j) v[j] = bf2f(sv[j]);
  if (m0[0] == 1) v[0] = -INFINITY;
  if (m0[1] == 1) v[1] = -INFINITY;
  if (m0[2] == 1) v[2] = -INFINITY;
  if (m0[3] == 1) v[3] = -INFINITY;
  if (m1[0] == 1) v[4] = -INFINITY;
  if (m1[1] == 1) v[5] = -INFINITY;
  if (m1[2] == 1) v[6] = -INFINITY;
  if (m1[3] == 1) v[7] = -INFINITY;
  float mx = v[0];
#pragma unroll
  for (int j = 1; j < 8; ++j) mx = fmaxf(mx, v[j]);
#pragma unroll
  for (int o = 32; o; o >>= 1) mx = fmaxf(mx, __shfl_xor(mx, o));
  float e[8], s = 0.0f;
#pragma unroll
  for (int j = 0; j < 8; ++j) {
    e[j] = expf(v[j] - mx);
    s += e[j];
  }
#pragma unroll
  for (int o = 32; o; o >>= 1) s += __shfl_xor(s, o);
  const float inv = 1.0f / s;
  bf16x8 o8;
#pragma unroll
  for (int j = 0; j < 8; ++j) o8[j] = f2bf(e[j] * inv);
  *reinterpret_cast<bf16x8*>(sp) = o8;
}

// ---------- reduce KSPLIT bf16 partials + bias + LayerNorm, vectorized ----------
__global__ __launch_bounds__(192) void ln_v(const __hip_bfloat16* __restrict__ yp,
                                            const float* __restrict__ bo,
                                            const float* __restrict__ gamma,
                                            const float* __restrict__ beta,
                                            float* __restrict__ out) {
  const long nY = (long)B_ * S_ * E_;
  const long base = (long)blockIdx.x * E_;
  const int t = threadIdx.x;
  const int c0 = t * 4;
  float a[4];
  {
    float4 bv = *reinterpret_cast<const float4*>(bo + c0);
    a[0] = bv.x; a[1] = bv.y; a[2] = bv.z; a[3] = bv.w;
  }
#pragma unroll
  for (int k = 0; k < KSPLIT; ++k) {
    bf16x4 v = *reinterpret_cast<const bf16x4*>((const short*)yp + k * nY + base + c0);
#pragma unroll
    for (int j = 0; j < 4; ++j) a[j] += bf2f(v[j]);
  }
  float s = a[0] + a[1] + a[2] + a[3];
  float ss = a[0] * a[0] + a[1] * a[1] + a[2] * a[2] + a[3] * a[3];
#pragma unroll
  for (int o = 32; o; o >>= 1) {
    s += __shfl_xor(s, o);
    ss += __shfl_xor(ss, o);
  }
  __shared__ float r1[3], r2[3];
  const int wave = t >> 6, lane = t & 63;
  if (lane == 0) { r1[wave] = s; r2[wave] = ss; }
  __syncthreads();
  s = r1[0] + r1[1] + r1[2];
  ss = r2[0] + r2[1] + r2[2];
  const float mu = s * (1.0f / E_);
  const float var = ss * (1.0f / E_) - mu * mu;
  const float rstd = rsqrtf(var + 1e-5f);
  float4 g = *reinterpret_cast<const float4*>(gamma + c0);
  float4 bt = *reinterpret_cast<const float4*>(beta + c0);
  float4 o4;
  o4.x = (a[0] - mu) * rstd * g.x + bt.x;
  o4.y = (a[1] - mu) * rstd * g.y + bt.y;
  o4.z = (a[2] - mu) * rstd * g.z + bt.z;
  o4.w = (a[3] - mu) * rstd * g.w + bt.w;
  *reinterpret_cast<float4*>(out + base + c0) = o4;
}

extern "C" void kernel_launch(void* const* d_in, const int* in_sizes, int n_in,
                              void* d_out, int out_size, void* d_ws, size_t ws_size,
                              hipStream_t stream) {
  const float* x = (const float*)d_in[0];
  const int* mask = (const int*)d_in[1];
  const float* Wh = (const float*)d_in[2];
  const float* bh = (const float*)d_in[3];
  const float* Wo = (const float*)d_in[4];
  const float* bo = (const float*)d_in[5];
  const float* gamma = (const float*)d_in[6];
  const float* beta = (const float*)d_in[7];
  float* out = (float*)d_out;

  // ---- workspace: phase-aliased regions (r5 layout, ~215.5 MB) ----
  const size_t nX = (size_t)B_ * S_ * E_;        // 3,145,728
  const size_t nP = (size_t)B_ * H_ * S_ * E_;   // 37,748,736
  const size_t nSc = (size_t)B_ * H_ * S_ * S_;  // 25,165,824
  char* base = (char*)d_ws;
  __hip_bfloat16* p = (__hip_bfloat16*)base;  // R_A: p, later cat
  __hip_bfloat16* cat = p;
  char* RB = base + nP * 2;
  __hip_bfloat16* pT = (__hip_bfloat16*)RB;       // R_B: pT, later ypart
  __hip_bfloat16* ypart = (__hip_bfloat16*)RB;
  char* RC = RB + nP * 2;
  __hip_bfloat16* xb = (__hip_bfloat16*)RC;       // R_C: xb+WhT, later scores/attn
  __hip_bfloat16* WhT = (__hip_bfloat16*)(RC + nX * 2);
  __hip_bfloat16* scores = (__hip_bfloat16*)RC;
  char* RD = RC + nSc * 2;
  __hip_bfloat16* WoT = (__hip_bfloat16*)RD;      // R_D: WoT

  dim3 t256(256);
  const float inv_sqrtE = 1.0f / sqrtf((float)E_);

  // 1. x -> bf16 (float4)
  cvt_v<<<dim3(nX / 1024), t256, 0, stream>>>(x, (short*)xb);
  // 2. WhT[h][o][e] = Wh[h][e][o]
  transpose_v<float, 4><<<dim3(12, 12, 12), t256, 0, stream>>>(
      Wh, (long)E_ * E_, (short*)WhT, (long)E_ * E_, E_, E_);
  // 3. WoT[o][k] = Wo[k][o]
  transpose_v<float, 4><<<dim3(12, 144, 1), t256, 0, stream>>>(
      Wo, 0, (short*)WoT, 0, HE_, E_);
  // 4. p = x·Wh + bh   (grid 6x4x96 = 2304)
  gemm_bt<true, true><<<dim3(6 * 4 * 96), t256, 0, stream>>>(
      xb, (long)S_ * E_, 0, E_, WhT, 0, (long)E_ * E_, E_, p, (long)H_ * S_ * E_,
      (long)S_ * E_, E_, bh, E_, H_, E_, 1.0f, 6, 4);
  // 5. pT[b,h,e,s] = p[b,h,s,e]
  transpose_v<short, 8><<<dim3(12, 8, 96), t256, 0, stream>>>(
      (const short*)p, (long)S_ * E_, (short*)pT, (long)S_ * E_, S_, E_);
  // 6. scores = (p·p^T)/sqrt(E)  (grid 4x4x96 = 1536)
  gemm_bt<true, false><<<dim3(4 * 4 * 96), t256, 0, stream>>>(
      p, (long)H_ * S_ * E_, (long)S_ * E_, E_, p, (long)H_ * S_ * E_, (long)S_ * E_, E_,
      scores, (long)H_ * S_ * S_, (long)S_ * S_, S_, nullptr, 0, H_, E_, inv_sqrtE, 4, 4);
  // 7. masked softmax in-place (wave-per-row)
  softmax_v<<<dim3(12288), t256, 0, stream>>>(scores, mask);
  // 8. o = attn·p -> cat  (grid 6x4x96 = 2304)
  gemm_bt<true, false><<<dim3(6 * 4 * 96), t256, 0, stream>>>(
      scores, (long)H_ * S_ * S_, (long)S_ * S_, S_, pT, (long)H_ * E_ * S_, (long)E_ * S_,
      S_, cat, (long)S_ * HE_, (long)E_, HE_, nullptr, 0, H_, S_, 1.0f, 6, 4);
  // 9. split-K GEMM4 (grid 6x32x6 = 1152, bf16 partials)
  gemm_bt<true, false><<<dim3(6 * 32 * KSPLIT), t256, 0, stream>>>(
      cat, 0, KCHUNK, HE_, WoT, 0, KCHUNK, HE_, ypart, 0, (long)B_ * S_ * E_, E_,
      nullptr, 0, KSPLIT, KCHUNK, 1.0f, 6, 32);
  // 10. reduce partials + bias + LayerNorm
  ln_v<<<dim3(B_ * S_), dim3(192), 0, stream>>>(ypart, bo, gamma, beta, out);
}

// Round 9
// 278.953 us; speedup vs baseline: 1.4107x; 1.1001x over previous
//
#include <hip/hip_runtime.h>
#include <hip/hip_bf16.h>
#include <math.h>

#define B_ 8
#define S_ 512
#define E_ 768
#define H_ 12
#define HE_ (H_ * E_)
#define KSPLIT 6
#define KCHUNK (HE_ / KSPLIT)  // 1536

typedef __attribute__((ext_vector_type(4))) short bf16x4;
typedef __attribute__((ext_vector_type(8))) short bf16x8;
typedef __attribute__((ext_vector_type(16))) float f32x16;

__device__ inline void gload_lds16(const void* g, void* l) {
  __builtin_amdgcn_global_load_lds(
      (const __attribute__((address_space(1))) unsigned int*)g,
      (__attribute__((address_space(3))) unsigned int*)l, 16, 0, 0);
}

__device__ inline float bf2f(short u) {
  union { float f; unsigned int i; } c;
  c.i = ((unsigned int)(unsigned short)u) << 16;
  return c.f;
}
__device__ inline short f2bf(float f) {
  __hip_bfloat16 h = __float2bfloat16(f);
  return *reinterpret_cast<short*>(&h);
}

// ---------- f32 -> bf16 convert, float4/lane ----------
__global__ __launch_bounds__(256) void cvt_v(const float* __restrict__ in,
                                             short* __restrict__ out) {
  const long i = ((long)blockIdx.x * 256 + threadIdx.x) * 4;
  float4 v = *reinterpret_cast<const float4*>(in + i);
  bf16x4 o;
  o[0] = f2bf(v.x); o[1] = f2bf(v.y); o[2] = f2bf(v.z); o[3] = f2bf(v.w);
  *reinterpret_cast<bf16x4*>(out + i) = o;
}

// ---------- per-batch mask compaction: idx[b][j] = j-th unmasked position ----------
// keep = (mask==0). cntp[2b] = cnt, cntp[2b+1] = cnt rounded up to 64 (<=512).
__global__ __launch_bounds__(512) void mask_scan(const int* __restrict__ mask,
                                                 int* __restrict__ idx,
                                                 int* __restrict__ cntp) {
  const int b = blockIdx.x;
  const int t = threadIdx.x;  // 0..511
  const int wave = t >> 6, lane = t & 63;
  const bool keep = (mask[b * S_ + t] == 0);
  unsigned long long bal = __ballot(keep);
  const int wprefix = __popcll(bal & ((1ull << lane) - 1ull));
  __shared__ int wt[8];
  if (lane == 0) wt[wave] = __popcll(bal);
  idx[b * S_ + t] = 0;  // default (pad entries point at row 0)
  __syncthreads();
  int off = 0, total = 0;
#pragma unroll
  for (int i = 0; i < 8; ++i) {
    off += (i < wave) ? wt[i] : 0;
    total += wt[i];
  }
  if (keep) idx[b * S_ + off + wprefix] = t;
  if (t == 0) {
    cntp[2 * b] = total;
    int pad = (total + 63) & ~63;
    cntp[2 * b + 1] = pad > S_ ? S_ : pad;
  }
}

// ---------- vectorized transpose: in [R][C] (T=float|bf16 as short) -> bf16 out [C][R] ----------
template <typename T, int VW>
__global__ __launch_bounds__(256) void transpose_v(const T* __restrict__ in, long inz,
                                                   short* __restrict__ out, long outz,
                                                   int R, int C) {
  __shared__ float t[64][65];
  in += (long)blockIdx.z * inz;
  out += (long)blockIdx.z * outz;
  const int bc = blockIdx.x * 64, br = blockIdx.y * 64;
  const int tid = threadIdx.x;
  constexpr int CPR = 64 / VW;
  constexpr int NP1 = 64 * CPR / 256;
#pragma unroll
  for (int ps = 0; ps < NP1; ++ps) {
    int q = tid + ps * 256;
    int r = q / CPR, c0 = (q % CPR) * VW;
    const T* src = in + (long)(br + r) * C + bc + c0;
    if constexpr (VW == 4) {
      float4 v = *reinterpret_cast<const float4*>(src);
      t[r][c0] = v.x; t[r][c0 + 1] = v.y; t[r][c0 + 2] = v.z; t[r][c0 + 3] = v.w;
    } else {
      bf16x8 v = *reinterpret_cast<const bf16x8*>(src);
#pragma unroll
      for (int j = 0; j < 8; ++j) t[r][c0 + j] = bf2f(v[j]);
    }
  }
  __syncthreads();
#pragma unroll
  for (int ps = 0; ps < 2; ++ps) {
    int q = tid + ps * 256;
    int e = q >> 3, s0 = (q & 7) * 8;
    bf16x8 o;
#pragma unroll
    for (int j = 0; j < 8; ++j) o[j] = f2bf(t[s0 + j][e]);
    *reinterpret_cast<bf16x8*>(out + (long)(bc + e) * R + br + s0) = o;
  }
}

// ---------- gather-transpose: pcT[z][e][j] = p[z][idx[b][j]][e], j < cnt_pad[b] ----------
__global__ __launch_bounds__(256) void transpose_gather(const short* __restrict__ p,
                                                        const int* __restrict__ gidx,
                                                        const int* __restrict__ cntp,
                                                        short* __restrict__ out) {
  const int z = blockIdx.z, b = z / H_;
  const int br = blockIdx.y * 64;  // j-chunk
  if (br >= cntp[2 * b + 1]) return;
  __shared__ float t[64][65];
  const short* in = p + (long)z * S_ * E_;
  short* o = out + (long)z * S_ * E_;
  const int bc = blockIdx.x * 64;  // e-chunk
  const int tid = threadIdx.x;
#pragma unroll
  for (int ps = 0; ps < 2; ++ps) {
    int q = tid + ps * 256;
    int r = q >> 3, c0 = (q & 7) * 8;
    int srow = gidx[b * S_ + br + r];
    bf16x8 v = *reinterpret_cast<const bf16x8*>(in + (long)srow * E_ + bc + c0);
#pragma unroll
    for (int j = 0; j < 8; ++j) t[r][c0 + j] = bf2f(v[j]);
  }
  __syncthreads();
#pragma unroll
  for (int ps = 0; ps < 2; ++ps) {
    int q = tid + ps * 256;
    int e = q >> 3, s0 = (q & 7) * 8;
    bf16x8 o8;
#pragma unroll
    for (int j = 0; j < 8; ++j) o8[j] = f2bf(t[s0 + j][e]);
    *reinterpret_cast<bf16x8*>(o + (long)(bc + e) * S_ + br + s0) = o8;
  }
}

// ---------- MFMA GEMM (32x32x16): C[M,N] = A[M,K] * (BT[N,K])^T ----------
// T1 XCD swizzle + chunk-XOR LDS swizzle. GATHER_B: B rows indirected via gidx
// (per-batch compacted key list) + early-exit tiles bn >= cnt_pad[b].
// K_FROM_CNT: K-loop bound = cnt_pad[b] (device-read, uniform).
template <bool OUT_BF16, bool ADD_BIAS, bool GATHER_B, bool K_FROM_CNT>
__global__ __launch_bounds__(256) void gemm_bt(
    const __hip_bfloat16* __restrict__ A, long As1, long As2, int lda,
    const __hip_bfloat16* __restrict__ BT, long Bs1, long Bs2, int ldb,
    void* __restrict__ Cv, long Cs1, long Cs2, int ldc,
    const float* __restrict__ bias, long biasS2, int zmod, int K, float scale,
    int nx, int ny, const int* __restrict__ gidx, const int* __restrict__ cntp) {
  constexpr int BM = 128, BN = 128, BK = 64;
  __shared__ __align__(16) __hip_bfloat16 sA[BM * BK];
  __shared__ __align__(16) __hip_bfloat16 sB[BN * BK];
  const int nwg = gridDim.x;
  const int cpx = nwg >> 3;
  const int id = blockIdx.x;
  const int w = (id & 7) * cpx + (id >> 3);
  const int bz = w / (nx * ny);
  const int rem = w - bz * nx * ny;
  const int by = rem / nx;
  const int bx = rem - by * nx;

  const int tid = threadIdx.x;
  const int wave = tid >> 6, lane = tid & 63;
  const int r32 = lane & 31, g2 = lane >> 5;
  const int zb = bz / zmod, zh = bz % zmod;
  const int bm = by * BM, bn = bx * BN;
  if (GATHER_B && bn >= cntp[2 * zb + 1]) return;  // uniform exit, pre-barrier
  int Keff = K;
  if (K_FROM_CNT) Keff = cntp[2 * zb + 1];
  A += (long)zb * As1 + (long)zh * As2;
  BT += (long)zb * Bs1 + (long)zh * Bs2;
  const int wm = (wave >> 1) * 64, wn = (wave & 1) * 64;
  const int swz = (r32 & 7) << 3;
  f32x16 acc[2][2] = {};
  const int e0 = tid * 8;

  // per-pass static staging coords (B row optionally gathered)
  int colp[4], rowp[4], growB[4];
#pragma unroll
  for (int p = 0; p < 4; ++p) {
    int ee = p * 2048 + e0;
    int row = ee >> 6;
    rowp[p] = row;
    colp[p] = (ee & 63) ^ ((row & 7) << 3);
    growB[p] = GATHER_B ? gidx[zb * S_ + bn + row] : (bn + row);
  }

  for (int k0 = 0; k0 < Keff; k0 += BK) {
#pragma unroll
    for (int p = 0; p < 4; ++p) {
      int ee = p * 2048 + e0;
      gload_lds16(A + (long)(bm + rowp[p]) * lda + (k0 + colp[p]), (char*)sA + ee * 2);
      gload_lds16(BT + (long)growB[p] * ldb + (k0 + colp[p]), (char*)sB + ee * 2);
    }
    __syncthreads();
#pragma unroll
    for (int ks = 0; ks < 4; ++ks) {
      bf16x8 aw[2], bw[2];
#pragma unroll
      for (int ti = 0; ti < 2; ++ti) {
        int row = wm + ti * 32 + r32;
        int c = (ks * 16 + g2 * 8) ^ swz;
        aw[ti] = *(const bf16x8*)(const void*)(sA + row * BK + c);
      }
#pragma unroll
      for (int tj = 0; tj < 2; ++tj) {
        int row = wn + tj * 32 + r32;
        int c = (ks * 16 + g2 * 8) ^ swz;
        bw[tj] = *(const bf16x8*)(const void*)(sB + row * BK + c);
      }
#pragma unroll
      for (int ti = 0; ti < 2; ++ti)
#pragma unroll
        for (int tj = 0; tj < 2; ++tj)
          acc[ti][tj] =
              __builtin_amdgcn_mfma_f32_32x32x16_bf16(aw[ti], bw[tj], acc[ti][tj], 0, 0, 0);
    }
    __syncthreads();
  }

  float* Cf = (float*)Cv;
  __hip_bfloat16* Cb = (__hip_bfloat16*)Cv;
  const long cbase = (long)zb * Cs1 + (long)zh * Cs2;
#pragma unroll
  for (int ti = 0; ti < 2; ++ti)
#pragma unroll
    for (int tj = 0; tj < 2; ++tj) {
      const int colv = bn + wn + tj * 32 + r32;
      const float bv = ADD_BIAS ? bias[(long)zh * biasS2 + colv] : 0.0f;
#pragma unroll
      for (int r = 0; r < 16; ++r) {
        int rowv = bm + wm + ti * 32 + (r & 3) + 8 * (r >> 2) + 4 * g2;
        float v = acc[ti][tj][r] * scale + bv;
        long off = cbase + (long)rowv * ldc + colv;
        if (OUT_BF16)
          Cb[off] = __float2bfloat16(v);
        else
          Cf[off] = v;
      }
    }
}

// ---------- softmax over compacted row (width cnt[b]), wave-per-row, IN-PLACE ----------
__global__ __launch_bounds__(256) void softmax_v(__hip_bfloat16* __restrict__ scores,
                                                 const int* __restrict__ cntp) {
  const int wave = threadIdx.x >> 6, lane = threadIdx.x & 63;
  const long row = (long)blockIdx.x * 4 + wave;
  const int b = (int)(row / ((long)H_ * S_));
  const int cnt = cntp[2 * b];
  short* sp = (short*)scores + row * S_ + lane * 8;
  bf16x8 sv = *reinterpret_cast<const bf16x8*>(sp);
  const int j0 = lane * 8;
  float v[8];
#pragma unroll
  for (int j = 0; j < 8; ++j) v[j] = (j0 + j < cnt) ? bf2f(sv[j]) : -INFINITY;
  float mx = v[0];
#pragma unroll
  for (int j = 1; j < 8; ++j) mx = fmaxf(mx, v[j]);
#pragma unroll
  for (int o = 32; o; o >>= 1) mx = fmaxf(mx, __shfl_xor(mx, o));
  float e[8], s = 0.0f;
#pragma unroll
  for (int j = 0; j < 8; ++j) {
    e[j] = expf(v[j] - mx);
    s += e[j];
  }
#pragma unroll
  for (int o = 32; o; o >>= 1) s += __shfl_xor(s, o);
  const float inv = 1.0f / s;
  bf16x8 o8;
#pragma unroll
  for (int j = 0; j < 8; ++j) o8[j] = f2bf(e[j] * inv);
  *reinterpret_cast<bf16x8*>(sp) = o8;
}

// ---------- reduce KSPLIT bf16 partials + bias + LayerNorm, vectorized ----------
__global__ __launch_bounds__(192) void ln_v(const __hip_bfloat16* __restrict__ yp,
                                            const float* __restrict__ bo,
                                            const float* __restrict__ gamma,
                                            const float* __restrict__ beta,
                                            float* __restrict__ out) {
  const long nY = (long)B_ * S_ * E_;
  const long base = (long)blockIdx.x * E_;
  const int t = threadIdx.x;
  const int c0 = t * 4;
  float a[4];
  {
    float4 bv = *reinterpret_cast<const float4*>(bo + c0);
    a[0] = bv.x; a[1] = bv.y; a[2] = bv.z; a[3] = bv.w;
  }
#pragma unroll
  for (int k = 0; k < KSPLIT; ++k) {
    bf16x4 v = *reinterpret_cast<const bf16x4*>((const short*)yp + k * nY + base + c0);
#pragma unroll
    for (int j = 0; j < 4; ++j) a[j] += bf2f(v[j]);
  }
  float s = a[0] + a[1] + a[2] + a[3];
  float ss = a[0] * a[0] + a[1] * a[1] + a[2] * a[2] + a[3] * a[3];
#pragma unroll
  for (int o = 32; o; o >>= 1) {
    s += __shfl_xor(s, o);
    ss += __shfl_xor(ss, o);
  }
  __shared__ float r1[3], r2[3];
  const int wave = t >> 6, lane = t & 63;
  if (lane == 0) { r1[wave] = s; r2[wave] = ss; }
  __syncthreads();
  s = r1[0] + r1[1] + r1[2];
  ss = r2[0] + r2[1] + r2[2];
  const float mu = s * (1.0f / E_);
  const float var = ss * (1.0f / E_) - mu * mu;
  const float rstd = rsqrtf(var + 1e-5f);
  float4 g = *reinterpret_cast<const float4*>(gamma + c0);
  float4 bt = *reinterpret_cast<const float4*>(beta + c0);
  float4 o4;
  o4.x = (a[0] - mu) * rstd * g.x + bt.x;
  o4.y = (a[1] - mu) * rstd * g.y + bt.y;
  o4.z = (a[2] - mu) * rstd * g.z + bt.z;
  o4.w = (a[3] - mu) * rstd * g.w + bt.w;
  *reinterpret_cast<float4*>(out + base + c0) = o4;
}

extern "C" void kernel_launch(void* const* d_in, const int* in_sizes, int n_in,
                              void* d_out, int out_size, void* d_ws, size_t ws_size,
                              hipStream_t stream) {
  const float* x = (const float*)d_in[0];
  const int* mask = (const int*)d_in[1];
  const float* Wh = (const float*)d_in[2];
  const float* bh = (const float*)d_in[3];
  const float* Wo = (const float*)d_in[4];
  const float* bo = (const float*)d_in[5];
  const float* gamma = (const float*)d_in[6];
  const float* beta = (const float*)d_in[7];
  float* out = (float*)d_out;

  // ---- workspace: phase-aliased regions (~215.6 MB) ----
  const size_t nX = (size_t)B_ * S_ * E_;
  const size_t nWh = (size_t)H_ * E_ * E_;
  const size_t nP = (size_t)B_ * H_ * S_ * E_;
  const size_t nSc = (size_t)B_ * H_ * S_ * S_;
  char* base = (char*)d_ws;
  __hip_bfloat16* p = (__hip_bfloat16*)base;  // R_A: p, later cat
  __hip_bfloat16* cat = p;
  char* RB = base + nP * 2;
  __hip_bfloat16* pcT = (__hip_bfloat16*)RB;      // R_B: compacted p^T, later ypart
  __hip_bfloat16* ypart = (__hip_bfloat16*)RB;
  char* RC = RB + nP * 2;
  __hip_bfloat16* xb = (__hip_bfloat16*)RC;       // R_C: xb+WhT, later scores/attn
  __hip_bfloat16* WhT = (__hip_bfloat16*)(RC + nX * 2);
  __hip_bfloat16* scores = (__hip_bfloat16*)RC;
  char* RD = RC + nSc * 2;
  __hip_bfloat16* WoT = (__hip_bfloat16*)RD;      // R_D: WoT
  int* idx = (int*)(RD + nWh * 2);                // 16 KB
  int* cntp = idx + B_ * S_;                      // 16 ints

  dim3 t256(256);
  const float inv_sqrtE = 1.0f / sqrtf((float)E_);

  // 0. mask compaction
  mask_scan<<<dim3(B_), dim3(512), 0, stream>>>(mask, idx, cntp);
  // 1. x -> bf16
  cvt_v<<<dim3(nX / 1024), t256, 0, stream>>>(x, (short*)xb);
  // 2. WhT[h][o][e] = Wh[h][e][o]
  transpose_v<float, 4><<<dim3(12, 12, 12), t256, 0, stream>>>(
      Wh, (long)E_ * E_, (short*)WhT, (long)E_ * E_, E_, E_);
  // 3. WoT[o][k] = Wo[k][o]
  transpose_v<float, 4><<<dim3(12, 144, 1), t256, 0, stream>>>(
      Wo, 0, (short*)WoT, 0, HE_, E_);
  // 4. p = x·Wh + bh   (grid 6x4x96 = 2304)
  gemm_bt<true, true, false, false><<<dim3(6 * 4 * 96), t256, 0, stream>>>(
      xb, (long)S_ * E_, 0, E_, WhT, 0, (long)E_ * E_, E_, p, (long)H_ * S_ * E_,
      (long)S_ * E_, E_, bh, E_, H_, E_, 1.0f, 6, 4, nullptr, nullptr);
  // 5. scores[:, j] = p · p[idx[j],:]^T / sqrt(E)   (gathered-B, early-exit tiles)
  gemm_bt<true, false, true, false><<<dim3(4 * 4 * 96), t256, 0, stream>>>(
      p, (long)H_ * S_ * E_, (long)S_ * E_, E_, p, (long)H_ * S_ * E_, (long)S_ * E_, E_,
      scores, (long)H_ * S_ * S_, (long)S_ * S_, S_, nullptr, 0, H_, E_, inv_sqrtE, 4, 4,
      idx, cntp);
  // 6. softmax over compacted width cnt[b], in-place
  softmax_v<<<dim3(12288), t256, 0, stream>>>(scores, cntp);
  // 7. pcT[b,h,e,j] = p[b,h,idx[j],e]  (gather-transpose, skip tiles >= cnt_pad)
  transpose_gather<<<dim3(12, 8, 96), t256, 0, stream>>>((const short*)p, idx, cntp,
                                                         (short*)pcT);
  // 8. o = attn_c · pc -> cat   (K bound = cnt_pad[b], device-read)
  gemm_bt<true, false, false, true><<<dim3(6 * 4 * 96), t256, 0, stream>>>(
      scores, (long)H_ * S_ * S_, (long)S_ * S_, S_, pcT, (long)H_ * E_ * S_,
      (long)E_ * S_, S_, cat, (long)S_ * HE_, (long)E_, HE_, nullptr, 0, H_, S_, 1.0f,
      6, 4, nullptr, cntp);
  // 9. split-K GEMM4 (grid 6x32x6 = 1152, bf16 partials)
  gemm_bt<true, false, false, false><<<dim3(6 * 32 * KSPLIT), t256, 0, stream>>>(
      cat, 0, KCHUNK, HE_, WoT, 0, KCHUNK, HE_, ypart, 0, (long)B_ * S_ * E_, E_,
      nullptr, 0, KSPLIT, KCHUNK, 1.0f, 6, 32, nullptr, nullptr);
  // 10. reduce partials + bias + LayerNorm
  ln_v<<<dim3(B_ * S_), dim3(192), 0, stream>>>(ypart, bo, gamma, beta, out);
}